// Round 16
// baseline (266.790 us; speedup 1.0000x reference)
//
#include <hip/hip_runtime.h>
#include <cstdint>
#include <cstddef>

// Problem constants (PrefixDecoderBlock): B=2, L=2048, d_model=1024, H=16, hd=64, d_ff=4096
#define DM   1024
#define NH   16
#define HD   64
#define DFF  4096
#define BB   2
#define LL   2048
#define MM   (BB*LL)   // 4096 rows total

using short8 = __attribute__((ext_vector_type(8))) short;   // 8 bf16 (4 VGPRs) — MFMA A/B frag
using f32x4  = __attribute__((ext_vector_type(4))) float;   // MFMA C/D frag

// RNE float -> bf16
__device__ __forceinline__ unsigned short f2bf(float f) {
  union { float f; uint32_t u; } v; v.f = f;
  uint32_t u = v.u;
  uint32_t r = (u + 0x7fffu + ((u >> 16) & 1u)) >> 16;
  return (unsigned short)r;
}

// pack 2 f32 -> 2 bf16 (RNE): lo=a, hi=b
__device__ __forceinline__ uint32_t cvtpk_bf16(float a, float b) {
  uint32_t r;
  asm("v_cvt_pk_bf16_f32 %0, %1, %2" : "=v"(r) : "v"(a), "v"(b));
  return r;
}

// raw 2^x (v_exp_f32)
__device__ __forceinline__ float exp2_fast(float x) {
  float r;
  asm("v_exp_f32 %0, %1" : "=v"(r) : "v"(x));
  return r;
}

// raw 1/x (v_rcp_f32, approx — fine for gelu)
__device__ __forceinline__ float rcp_fast(float x) {
  float r;
  asm("v_rcp_f32 %0, %1" : "=v"(r) : "v"(x));
  return r;
}

__device__ __forceinline__ float gelu_tanh(float v) {
  float y = v * (0.7978845608028654f + 0.035677408136300125f * v * v);
  float e = exp2_fast(y * 2.885390081777927f);          // e^(2y)
  float tnh = 1.0f - 2.0f * rcp_fast(1.0f + e);
  return 0.5f * v * (1.0f + tnh);
}

#define GLDS16(gp, lp) \
  __builtin_amdgcn_global_load_lds((const __attribute__((address_space(1))) uint32_t*)(gp), \
                                   (__attribute__((address_space(3))) uint32_t*)(lp), 16, 0, 0)

// ---------------- elementwise fp32 -> bf16 convert (weights) ----------------
__global__ __launch_bounds__(256) void convert_f32_bf16(const float* __restrict__ in,
                                                        unsigned short* __restrict__ out, int n4) {
  int i = blockIdx.x * 256 + threadIdx.x;
  if (i < n4) {
    float4 v = ((const float4*)in)[i];
    ushort4 o;
    o.x = f2bf(v.x); o.y = f2bf(v.y); o.z = f2bf(v.z); o.w = f2bf(v.w);
    ((ushort4*)out)[i] = o;
  }
}

// ---------------- LayerNorm: fp32 [rows][1024] -> bf16 ----------------
__global__ __launch_bounds__(256) void ln_kernel(const float* __restrict__ x,
                                                 const float* __restrict__ w,
                                                 const float* __restrict__ b,
                                                 unsigned short* __restrict__ out) {
  int row = blockIdx.x, t = threadIdx.x;
  float4 v = ((const float4*)(x + (size_t)row * DM))[t];
  float s  = v.x + v.y + v.z + v.w;
  float sq = v.x*v.x + v.y*v.y + v.z*v.z + v.w*v.w;
  #pragma unroll
  for (int o = 32; o; o >>= 1) { s += __shfl_down(s, o); sq += __shfl_down(sq, o); }
  __shared__ float sh[8];
  if ((t & 63) == 0) { sh[t >> 6] = s; sh[4 + (t >> 6)] = sq; }
  __syncthreads();
  float S  = sh[0] + sh[1] + sh[2] + sh[3];
  float SQ = sh[4] + sh[5] + sh[6] + sh[7];
  float mu  = S * (1.0f / DM);
  float var = SQ * (1.0f / DM) - mu * mu;
  float rs  = rsqrtf(var + 1e-5f);
  float4 wv = ((const float4*)w)[t];
  float4 bv = ((const float4*)b)[t];
  ushort4 o;
  o.x = f2bf((v.x - mu) * rs * wv.x + bv.x);
  o.y = f2bf((v.y - mu) * rs * wv.y + bv.y);
  o.z = f2bf((v.z - mu) * rs * wv.z + bv.z);
  o.w = f2bf((v.w - mu) * rs * wv.w + bv.w);
  ((ushort4*)(out + (size_t)row * DM))[t] = o;
}

// ---------------- gemm8: 256x256 tile, 8 waves, 4-phase counted-vmcnt pipeline ----------------
// For M%256==0, N%256==0, K%64==0, K/64>=2. A:[M][lda], W:[N][ldb] bf16.
// K-tile (256x64 each of A,B) split into 4 half-tiles staged in order
// [A-h0, B-h0, A-h1, B-h1] (2 GLDS16 each). Phase q of tile t computes C-quadrant
// q: (ah,bh) = (0,0),(1,0),(1,1),(0,1) — all 8 waves cooperate on one 128x128
// quadrant (wave = 32 rows x 64 cols, 16 MFMA). Phase entry: s_waitcnt vmcnt(4)
// (oldest-4 = needed half landed; HW retires in issue order) -> s_barrier (all
// waves' loads landed => whole half in LDS) -> issue half q of tile t+1 into
// buf^1 (that buffer's reads finished >=4 phases ago) -> sched_barrier -> MFMA.
// vmcnt never drains to 0 mid-loop; last tile uses 4/2/0/0. XOR-swizzled LDS.
// EPI 0: bf16(acc+bias); EPI 2: bf16(gelu_tanh(acc+bias))
template <int EPI>
__global__ __launch_bounds__(512) void gemm8(const unsigned short* __restrict__ A,
                                             const unsigned short* __restrict__ Bw,
                                             const float* __restrict__ bias,
                                             unsigned short* __restrict__ Cout,
                                             int M, int N, int K, int lda, int ldb) {
  __shared__ unsigned short As[2][2][128 * 64];   // [buf][half] 64 KB
  __shared__ unsigned short Bs[2][2][128 * 64];   // 64 KB
  const int t = threadIdx.x;
  const int l = t & 63, lr = l & 15, lg = l >> 4;
  const int wid = t >> 6;
  const int wr = wid & 3;          // wave's 32-row quarter within a quadrant
  const int wc = wid >> 2;         // wave's 64-col half within a quadrant

  // T1: XCD-contiguous remap (bijective; totals here are %8==0)
  int bx = blockIdx.x, by = blockIdx.y;
  {
    const int gx = gridDim.x;
    const int total = gx * gridDim.y;
    if ((total & 7) == 0) {
      int lin = by * gx + bx;
      int lin2 = (lin & 7) * (total >> 3) + (lin >> 3);
      bx = lin2 % gx;
      by = lin2 / gx;
    }
  }
  const int m0 = by * 256, n0 = bx * 256;

  f32x4 acc[4][2][4];
  #pragma unroll
  for (int q = 0; q < 4; ++q)
    #pragma unroll
    for (int fr = 0; fr < 2; ++fr)
      #pragma unroll
      for (int fc = 0; fc < 4; ++fc) acc[q][fr][fc] = {0.f, 0.f, 0.f, 0.f};

  // staging: thread t covers row (t>>3) of each 64-row group, seg (t&7), XOR-preswizzled src
  const int rowt = t >> 3, sw = (t & 7) ^ (rowt & 7);
  const unsigned short* Ag = A  + (size_t)(m0 + rowt) * lda + sw * 8;
  const unsigned short* Bg = Bw + (size_t)(n0 + rowt) * ldb + sw * 8;
  const size_t r64A = (size_t)64 * lda;
  const size_t r64B = (size_t)64 * ldb;

  const int rs = lr & 7;
  const int segA = (lg ^ rs) * 8;        // k 0..31 half
  const int segB4 = ((lg + 4) ^ rs) * 8; // k 32..63 half

  const int nt = K >> 6;

  auto stageA = [&](int kt, int buf, int h) {
    const int k0 = kt << 6;
    char* d = (char*)&As[buf][h][0] + t * 16;
    const unsigned short* g = Ag + (size_t)(h * 128) * lda + k0;
    GLDS16(g,        d);
    GLDS16(g + r64A, d + 8192);
  };
  auto stageB = [&](int kt, int buf, int h) {
    const int k0 = kt << 6;
    char* d = (char*)&Bs[buf][h][0] + t * 16;
    const unsigned short* g = Bg + (size_t)(h * 128) * ldb + k0;
    GLDS16(g,        d);
    GLDS16(g + r64B, d + 8192);
  };

  // prologue: tile 0 in consumption order (8 loads in flight)
  stageA(0, 0, 0); stageB(0, 0, 0); stageA(0, 0, 1); stageB(0, 0, 1);

  for (int kt = 0; kt < nt; ++kt) {
    const int cur = kt & 1, nxt = cur ^ 1;
    const bool more = (kt + 1 < nt);
    #pragma unroll
    for (int q = 0; q < 4; ++q) {
      if (more) {
        asm volatile("s_waitcnt vmcnt(4)" ::: "memory");
      } else {
        if (q == 0)      asm volatile("s_waitcnt vmcnt(4)" ::: "memory");
        else if (q == 1) asm volatile("s_waitcnt vmcnt(2)" ::: "memory");
        else             asm volatile("s_waitcnt vmcnt(0)" ::: "memory");
      }
      __builtin_amdgcn_s_barrier();
      if (more) {
        if (q == 0)      stageA(kt + 1, nxt, 0);
        else if (q == 1) stageB(kt + 1, nxt, 0);
        else if (q == 2) stageA(kt + 1, nxt, 1);
        else             stageB(kt + 1, nxt, 1);
      }
      __builtin_amdgcn_sched_barrier(0);
      const int ah = (q == 1 || q == 2) ? 1 : 0;
      const int bh = (q >= 2) ? 1 : 0;
      const unsigned short* Ab = &As[cur][ah][0];
      const unsigned short* Bb = &Bs[cur][bh][0];
      short8 bf[4][2];
      #pragma unroll
      for (int fc = 0; fc < 4; ++fc) {
        const int row = wc * 64 + fc * 16 + lr;
        bf[fc][0] = *(const short8*)&Bb[row * 64 + segA];
        bf[fc][1] = *(const short8*)&Bb[row * 64 + segB4];
      }
      short8 af[2][2];
      #pragma unroll
      for (int fr = 0; fr < 2; ++fr) {
        const int row = wr * 32 + fr * 16 + lr;
        af[fr][0] = *(const short8*)&Ab[row * 64 + segA];
        af[fr][1] = *(const short8*)&Ab[row * 64 + segB4];
      }
      __builtin_amdgcn_s_setprio(1);
      #pragma unroll
      for (int fr = 0; fr < 2; ++fr)
        #pragma unroll
        for (int fc = 0; fc < 4; ++fc) {
          acc[q][fr][fc] = __builtin_amdgcn_mfma_f32_16x16x32_bf16(af[fr][0], bf[fc][0], acc[q][fr][fc], 0, 0, 0);
          acc[q][fr][fc] = __builtin_amdgcn_mfma_f32_16x16x32_bf16(af[fr][1], bf[fc][1], acc[q][fr][fc], 0, 0, 0);
        }
      __builtin_amdgcn_s_setprio(0);
    }
  }

  #pragma unroll
  for (int q = 0; q < 4; ++q) {
    const int ah = (q == 1 || q == 2) ? 1 : 0;
    const int bh = (q >= 2) ? 1 : 0;
    #pragma unroll
    for (int fr = 0; fr < 2; ++fr) {
      int row = m0 + ah * 128 + wr * 32 + fr * 16 + lg * 4;
      #pragma unroll
      for (int fc = 0; fc < 4; ++fc) {
        int col = n0 + bh * 128 + wc * 64 + fc * 16 + lr;
        float bv = bias[col];
        #pragma unroll
        for (int r = 0; r < 4; ++r) {
          float v = acc[q][fr][fc][r] + bv;
          size_t idx = (size_t)(row + r) * N + col;
          if (EPI == 0) {
            Cout[idx] = f2bf(v);
          } else {
            Cout[idx] = f2bf(gelu_tanh(v));
          }
        }
      }
    }
  }
}

// ---------------- GEMM (2-phase): C[m][n] = A[m][:]·W[n][:] — small-N shapes ----------------
// Tile BM x 64, BK=64; 4 waves; XOR-swizzled LDS both sides (conflicts: 0, R10).
// EPI 0: bf16(acc+bias); EPI 1: f32 res+acc+bias; EPI 2: bf16(gelu_tanh(acc+bias));
// EPI 3: f32 Cout += acc (no bias; split-K accumulate pass)
template <int EPI, int BM>
__global__ __launch_bounds__(256) void gemm_bt(const unsigned short* __restrict__ A,
                                               const unsigned short* __restrict__ Bw,
                                               const float* __restrict__ bias,
                                               const float* __restrict__ res,
                                               void* __restrict__ Cout,
                                               int M, int N, int K, int lda, int ldb) {
  constexpr int MI   = BM / 32;
  constexpr int ABUF = BM * 64;
  __shared__ unsigned short As[2 * ABUF];
  __shared__ unsigned short Bs[2 * 64 * 64];
  const int t = threadIdx.x;
  const int l = t & 63, lr = l & 15, lg = l >> 4;
  const int w = t >> 6, wm = w >> 1, wn = w & 1;

  int bx = blockIdx.x, by = blockIdx.y;
  {
    const int gx = gridDim.x;
    const int total = gx * gridDim.y;
    if ((total & 7) == 0) {
      int lin = by * gx + bx;
      int lin2 = (lin & 7) * (total >> 3) + (lin >> 3);
      bx = lin2 % gx;
      by = lin2 / gx;
    }
  }
  const int m0 = by * BM, n0 = bx * 64;

  f32x4 acc[MI][2];
  #pragma unroll
  for (int mi = 0; mi < MI; ++mi)
    #pragma unroll
    for (int ni = 0; ni < 2; ++ni) acc[mi][ni] = {0.f, 0.f, 0.f, 0.f};

  const int rowt = t >> 3, sw = (t & 7) ^ (rowt & 7);
  const unsigned short* Ag = A  + (size_t)(m0 + rowt) * lda + sw * 8;
  const unsigned short* Bg = Bw + (size_t)(n0 + rowt) * ldb + sw * 8;
  char* AsB = (char*)As + t * 16;
  char* BsB = (char*)Bs + t * 16;
  const size_t r32A = (size_t)32 * lda;
  const size_t r32B = (size_t)32 * ldb;

  const int rs = lr & 7;
  const int segA = (lg ^ rs) * 8;
  const int segB = ((lg + 4) ^ rs) * 8;

  #pragma unroll
  for (int g = 0; g < MI; ++g) GLDS16(Ag + g * r32A, AsB + g * 4096);
  GLDS16(Bg,        BsB);
  GLDS16(Bg + r32B, BsB + 4096);

  int cur = 0;
  for (int k0 = 0; k0 < K; k0 += 64, cur ^= 1) {
    __syncthreads();
    const int kn = k0 + 64;
    if (kn < K) {
      char* An = AsB + (cur ^ 1) * (ABUF * 2);
      char* Bn = BsB + (cur ^ 1) * 8192;
      #pragma unroll
      for (int g = 0; g < MI; ++g) GLDS16(Ag + kn + g * r32A, An + g * 4096);
      GLDS16(Bg + kn,        Bn);
      GLDS16(Bg + kn + r32B, Bn + 4096);
    }
    const unsigned short* Ab = As + cur * ABUF;
    const unsigned short* Bb = Bs + cur * (64 * 64);
    short8 af[MI][2], bfr[2][2];
    #pragma unroll
    for (int mi = 0; mi < MI; ++mi) {
      const int row = wm * (BM / 2) + mi * 16 + lr;
      af[mi][0] = *(const short8*)&Ab[row * 64 + segA];
      af[mi][1] = *(const short8*)&Ab[row * 64 + segB];
    }
    #pragma unroll
    for (int ni = 0; ni < 2; ++ni) {
      const int row = wn * 32 + ni * 16 + lr;
      bfr[ni][0] = *(const short8*)&Bb[row * 64 + segA];
      bfr[ni][1] = *(const short8*)&Bb[row * 64 + segB];
    }
    #pragma unroll
    for (int mi = 0; mi < MI; ++mi)
      #pragma unroll
      for (int ni = 0; ni < 2; ++ni) {
        acc[mi][ni] = __builtin_amdgcn_mfma_f32_16x16x32_bf16(af[mi][0], bfr[ni][0], acc[mi][ni], 0, 0, 0);
        acc[mi][ni] = __builtin_amdgcn_mfma_f32_16x16x32_bf16(af[mi][1], bfr[ni][1], acc[mi][ni], 0, 0, 0);
      }
  }

  #pragma unroll
  for (int mi = 0; mi < MI; ++mi) {
    int row = m0 + wm * (BM / 2) + mi * 16 + lg * 4;
    #pragma unroll
    for (int ni = 0; ni < 2; ++ni) {
      int col = n0 + wn * 32 + ni * 16 + lr;
      float bv = (EPI == 3) ? 0.f : bias[col];
      #pragma unroll
      for (int r = 0; r < 4; ++r) {
        float v = acc[mi][ni][r] + bv;
        size_t idx = (size_t)(row + r) * N + col;
        if (EPI == 0) {
          ((unsigned short*)Cout)[idx] = f2bf(v);
        } else if (EPI == 1) {
          ((float*)Cout)[idx] = res[idx] + v;
        } else if (EPI == 2) {
          ((unsigned short*)Cout)[idx] = f2bf(gelu_tanh(v));
        } else {
          ((float*)Cout)[idx] += v;
        }
      }
    }
  }
}

// ---------------- V transpose: qkv[b][j][2048+h*64+d] -> vt[(b*16+h)*64+d][j] ----------------
__global__ __launch_bounds__(256) void vtrans_kernel(const unsigned short* __restrict__ qkv,
                                                     unsigned short* __restrict__ vt) {
  __shared__ unsigned short tile[64][72];
  int bh = blockIdx.y, b = bh >> 4, h = bh & 15;
  int j0 = blockIdx.x * 64, t = threadIdx.x;
  #pragma unroll
  for (int r = 0; r < 2; ++r) {
    int j = r * 32 + (t >> 3), d0 = (t & 7) * 8;
    short8 v = *(const short8*)(qkv + (size_t)(b * LL + j0 + j) * 3072 + 2048 + h * 64 + d0);
    #pragma unroll
    for (int e = 0; e < 8; ++e) tile[j][d0 + e] = (unsigned short)v[e];
  }
  __syncthreads();
  #pragma unroll
  for (int r = 0; r < 2; ++r) {
    int d = r * 32 + (t >> 3), j = (t & 7) * 8;
    short8 o;
    #pragma unroll
    for (int e = 0; e < 8; ++e) o[e] = (short)tile[j + e][d];
    *(short8*)(vt + (size_t)(bh * 64 + d) * LL + j0 + j) = o;
  }
}

// ---------------- Flash attention with prefix-decoder mask ----------------
// grid: (L/128, B*H), 8 waves x 512 threads; wave w owns q-rows i0+w*16 .. +15.
// allowed(i,j) = (j<m) | (i>=m & j<=i)
// SWAPPED QK^T; no-max softmax; row-sum via ones-column MFMA; dbuf K/V staging.
__global__ __launch_bounds__(512) void attn_kernel(const unsigned short* __restrict__ qkv,
                                                   const unsigned short* __restrict__ vt,
                                                   const int* __restrict__ prefix,
                                                   unsigned short* __restrict__ ctx) {
  __shared__ unsigned short Ks[2][64 * 64];
  __shared__ unsigned short Vs[2][64 * 64];
  __shared__ unsigned short Plds[8][16][72];
  const int t = threadIdx.x, w = t >> 6, l = t & 63, lr = l & 15, lg = l >> 4;
  const int bh = blockIdx.y, b = bh >> 4, h = bh & 15;
  const int ib = gridDim.x - 1 - blockIdx.x;
  const int i0 = ib * 128, iw = i0 + w * 16;
  const int m = *prefix;
  const float C = 0.125f * 1.44269504088896f;

  const int r0 = t >> 3, s0 = t & 7, swz = s0 ^ (r0 & 7);
  const unsigned short* Kg0 = qkv + (size_t)(b * LL + r0) * 3072 + DM + h * 64 + swz * 8;
  const unsigned short* Vg0 = vt + (size_t)(bh * 64 + r0) * LL + swz * 8;
  char* KdB = (char*)Ks + t * 16;
  char* VdB = (char*)Vs + t * 16;
  const int rs = lr & 7;
  const int segA = (lg ^ rs) * 8;
  const int segB = ((lg + 4) ^ rs) * 8;

  short8 qf[2];
  {
    const unsigned short* qrow = qkv + (size_t)(b * LL + iw + lr) * 3072 + h * 64;
    qf[0] = *(const short8*)(qrow + lg * 8);
    qf[1] = *(const short8*)(qrow + 32 + lg * 8);
  }
  short8 ones;
  #pragma unroll
  for (int e = 0; e < 8; ++e) ones[e] = (short)0x3F80;

  f32x4 Ot[4];
  #pragma unroll
  for (int dt = 0; dt < 4; ++dt) Ot[dt] = {0.f, 0.f, 0.f, 0.f};
  f32x4 Osum = {0.f, 0.f, 0.f, 0.f};

  const int jmax = (i0 + 128 <= m) ? m : (i0 + 128);
  const int nb = (jmax + 63) >> 6;
  const int i_abs = iw + lr;

  GLDS16(Kg0, KdB);
  GLDS16(Vg0, VdB);

  for (int c = 0; c < nb; ++c) {
    __syncthreads();
    if (c + 1 < nb) {
      const size_t jn = (size_t)(c + 1) * 64;
      const int pn = (c + 1) & 1;
      GLDS16(Kg0 + jn * 3072, KdB + pn * 8192);
      GLDS16(Vg0 + jn,        VdB + pn * 8192);
    }
    const int jt = c * 64, p = c & 1;

    f32x4 sc[4];
    #pragma unroll
    for (int nt = 0; nt < 4; ++nt) {
      sc[nt] = {0.f, 0.f, 0.f, 0.f};
      const int row = nt * 16 + lr;
      short8 kf0 = *(const short8*)&Ks[p][row * 64 + segA];
      short8 kf1 = *(const short8*)&Ks[p][row * 64 + segB];
      sc[nt] = __builtin_amdgcn_mfma_f32_16x16x32_bf16(kf0, qf[0], sc[nt], 0, 0, 0);
      sc[nt] = __builtin_amdgcn_mfma_f32_16x16x32_bf16(kf1, qf[1], sc[nt], 0, 0, 0);
    }
    const bool full = (jt + 64 <= m) || (iw >= m && jt + 64 <= iw + 1);
    #pragma unroll
    for (int nt = 0; nt < 4; ++nt) {
      float p0 = exp2_fast(sc[nt][0] * C);
      float p1 = exp2_fast(sc[nt][1] * C);
      float p2 = exp2_fast(sc[nt][2] * C);
      float p3 = exp2_fast(sc[nt][3] * C);
      if (!full) {
        const int jb = jt + nt * 16 + lg * 4;
        const bool causal_i = (i_abs >= m);
        p0 = ((jb + 0 < m) || (causal_i && jb + 0 <= i_abs)) ? p0 : 0.f;
        p1 = ((jb + 1 < m) || (causal_i && jb + 1 <= i_abs)) ? p1 : 0.f;
        p2 = ((jb + 2 < m) || (causal_i && jb + 2 <= i_abs)) ? p2 : 0.f;
        p3 = ((jb + 3 < m) || (causal_i && jb + 3 <= i_abs)) ? p3 : 0.f;
      }
      uint2 pk;
      pk.x = cvtpk_bf16(p0, p1);
      pk.y = cvtpk_bf16(p2, p3);
      *(uint2*)&Plds[w][lr][nt * 16 + lg * 4] = pk;
    }
    short8 paf0 = *(const short8*)&Plds[w][lr][lg * 8];
    short8 paf1 = *(const short8*)&Plds[w][lr][32 + lg * 8];
    #pragma unroll
    for (int dt = 0; dt < 4; ++dt) {
      const int row = dt * 16 + lr;
      short8 vf0 = *(const short8*)&Vs[p][row * 64 + segA];
      short8 vf1 = *(const short8*)&Vs[p][row * 64 + segB];
      Ot[dt] = __builtin_amdgcn_mfma_f32_16x16x32_bf16(paf0, vf0, Ot[dt], 0, 0, 0);
      Ot[dt] = __builtin_amdgcn_mfma_f32_16x16x32_bf16(paf1, vf1, Ot[dt], 0, 0, 0);
    }
    Osum = __builtin_amdgcn_mfma_f32_16x16x32_bf16(paf0, ones, Osum, 0, 0, 0);
    Osum = __builtin_amdgcn_mfma_f32_16x16x32_bf16(paf1, ones, Osum, 0, 0, 0);
  }
  #pragma unroll
  for (int r = 0; r < 4; ++r) {
    float inv = 1.0f / Osum[r];
    size_t row = (size_t)(b * LL + iw + lg * 4 + r);
    #pragma unroll
    for (int dt = 0; dt < 4; ++dt)
      ctx[row * DM + h * 64 + dt * 16 + lr] = f2bf(Ot[dt][r] * inv);
  }
}

// ---------------- launch ----------------
// Base workspace layout (56 MiB, lifetime-disjoint aliases):
//   [0, 8)  slab : h1, ctx, h2    [8,24) x2 fp32; vt alias [8,16)
//   [24,32) wslab (in_proj/out_w/fc1_w bf16)
//   [32,56) qkv; after attn: wfc2 [32,40) + ffh [40,56)
// If ws_size >= 72 MiB: ffmid [40,72) (32 MiB) -> single-pass fc1/fc2.
extern "C" void kernel_launch(void* const* d_in, const int* in_sizes, int n_in,
                              void* d_out, int out_size, void* d_ws, size_t ws_size,
                              hipStream_t stream) {
  const float* x        = (const float*)d_in[0];
  const float* ln1_w    = (const float*)d_in[1];
  const float* ln1_b    = (const float*)d_in[2];
  const float* in_proj_w= (const float*)d_in[3];
  const float* in_proj_b= (const float*)d_in[4];
  const float* out_w    = (const float*)d_in[5];
  const float* out_b    = (const float*)d_in[6];
  const float* ln2_w    = (const float*)d_in[7];
  const float* ln2_b    = (const float*)d_in[8];
  const float* fc1_w    = (const float*)d_in[9];
  const float* fc1_b    = (const float*)d_in[10];
  const float* fc2_w    = (const float*)d_in[11];
  const float* fc2_b    = (const float*)d_in[12];
  const int*   prefix   = (const int*)d_in[13];
  float* outp = (float*)d_out;

  char* ws = (char*)d_ws;
  unsigned short* slab  = (unsigned short*)ws;                          // [0,8)
  float*          x2    = (float*)(ws + ((size_t)8 << 20));             // [8,24)
  unsigned short* vtb   = (unsigned short*)(ws + ((size_t)8 << 20));    // [8,16) alias
  unsigned short* wslab = (unsigned short*)(ws + ((size_t)24 << 20));   // [24,32)
  unsigned short* qkv   = (unsigned short*)(ws + ((size_t)32 << 20));   // [32,56)
  unsigned short* wfc2  = (unsigned short*)(ws + ((size_t)32 << 20));   // [32,40) alias
  unsigned short* ffh   = (unsigned short*)(ws + ((size_t)40 << 20));   // [40,56) alias
  const bool big = ws_size >= ((size_t)72 << 20);

  // --- attention half ---
  convert_f32_bf16<<<3072, 256, 0, stream>>>(in_proj_w, wslab, 3072 * 1024 / 4);
  ln_kernel<<<MM, 256, 0, stream>>>(x, ln1_w, ln1_b, slab);
  gemm8<0><<<dim3(3072 / 256, MM / 256), 512, 0, stream>>>(slab, wslab, in_proj_b, qkv, MM, 3072, 1024, 1024, 1024);
  vtrans_kernel<<<dim3(LL / 64, BB * NH), 256, 0, stream>>>(qkv, vtb);
  attn_kernel<<<dim3(LL / 128, BB * NH), 512, 0, stream>>>(qkv, vtb, prefix, slab);
  convert_f32_bf16<<<1024, 256, 0, stream>>>(out_w, wslab, 1024 * 1024 / 4);
  gemm_bt<1, 64><<<dim3(1024 / 64, MM / 64), 256, 0, stream>>>(slab, wslab, out_b, x, x2, MM, 1024, 1024, 1024, 1024);

  // --- FFN ---
  ln_kernel<<<MM, 256, 0, stream>>>(x2, ln2_w, ln2_b, slab);
  convert_f32_bf16<<<4096, 256, 0, stream>>>(fc1_w, wslab, 4096 * 1024 / 4);
  convert_f32_bf16<<<4096, 256, 0, stream>>>(fc2_w, wfc2, 1024 * 4096 / 4);  // qkv dead
  if (big) {
    // single-pass: ffmid = gelu(h2 @ fc1_w^T + b) [4096x4096, 32 MiB at [40,72)];
    // out = x2 + ffmid @ fc2_w^T + fc2_b (K=4096)
    unsigned short* ffmid = (unsigned short*)(ws + ((size_t)40 << 20));
    gemm8<2><<<dim3(4096 / 256, MM / 256), 512, 0, stream>>>(slab, wslab, fc1_b, ffmid, MM, 4096, 1024, 1024, 1024);
    gemm_bt<1, 64><<<dim3(1024 / 64, MM / 64), 256, 0, stream>>>(ffmid, wfc2, fc2_b, x2, outp, MM, 1024, 4096, 4096, 4096);
  } else {
    gemm_bt<2, 128><<<dim3(2048 / 64, MM / 128), 256, 0, stream>>>(slab, wslab, fc1_b, nullptr, ffh, MM, 2048, 1024, 1024, 1024);
    gemm_bt<1, 64><<<dim3(1024 / 64, MM / 64), 256, 0, stream>>>(ffh, wfc2, fc2_b, x2, outp, MM, 1024, 2048, 2048, 4096);
    gemm_bt<2, 128><<<dim3(2048 / 64, MM / 128), 256, 0, stream>>>(slab, wslab + (size_t)2048 * 1024, fc1_b + 2048, nullptr, ffh, MM, 2048, 1024, 1024, 1024);
    gemm_bt<3, 64><<<dim3(1024 / 64, MM / 64), 256, 0, stream>>>(ffh, wfc2 + 2048, nullptr, nullptr, outp, MM, 1024, 2048, 2048, 4096);
  }
}

// Round 17
// 223.026 us; speedup vs baseline: 1.1962x; 1.1962x over previous
//
#include <hip/hip_runtime.h>
#include <cstdint>
#include <cstddef>

// Problem constants (PrefixDecoderBlock): B=2, L=2048, d_model=1024, H=16, hd=64, d_ff=4096
#define DM   1024
#define NH   16
#define HD   64
#define DFF  4096
#define BB   2
#define LL   2048
#define MM   (BB*LL)   // 4096 rows total

using short8 = __attribute__((ext_vector_type(8))) short;   // 8 bf16 (4 VGPRs) — MFMA A/B frag
using f32x4  = __attribute__((ext_vector_type(4))) float;   // MFMA C/D frag

// RNE float -> bf16
__device__ __forceinline__ unsigned short f2bf(float f) {
  union { float f; uint32_t u; } v; v.f = f;
  uint32_t u = v.u;
  uint32_t r = (u + 0x7fffu + ((u >> 16) & 1u)) >> 16;
  return (unsigned short)r;
}

// pack 2 f32 -> 2 bf16 (RNE): lo=a, hi=b
__device__ __forceinline__ uint32_t cvtpk_bf16(float a, float b) {
  uint32_t r;
  asm("v_cvt_pk_bf16_f32 %0, %1, %2" : "=v"(r) : "v"(a), "v"(b));
  return r;
}

// raw 2^x (v_exp_f32)
__device__ __forceinline__ float exp2_fast(float x) {
  float r;
  asm("v_exp_f32 %0, %1" : "=v"(r) : "v"(x));
  return r;
}

// raw 1/x (v_rcp_f32, approx — fine for gelu)
__device__ __forceinline__ float rcp_fast(float x) {
  float r;
  asm("v_rcp_f32 %0, %1" : "=v"(r) : "v"(x));
  return r;
}

__device__ __forceinline__ float gelu_tanh(float v) {
  float y = v * (0.7978845608028654f + 0.035677408136300125f * v * v);
  float e = exp2_fast(y * 2.885390081777927f);          // e^(2y)
  float tnh = 1.0f - 2.0f * rcp_fast(1.0f + e);
  return 0.5f * v * (1.0f + tnh);
}

#define GLDS16(gp, lp) \
  __builtin_amdgcn_global_load_lds((const __attribute__((address_space(1))) uint32_t*)(gp), \
                                   (__attribute__((address_space(3))) uint32_t*)(lp), 16, 0, 0)

// ---------------- elementwise fp32 -> bf16 convert (weights) ----------------
__global__ __launch_bounds__(256) void convert_f32_bf16(const float* __restrict__ in,
                                                        unsigned short* __restrict__ out, int n4) {
  int i = blockIdx.x * 256 + threadIdx.x;
  if (i < n4) {
    float4 v = ((const float4*)in)[i];
    ushort4 o;
    o.x = f2bf(v.x); o.y = f2bf(v.y); o.z = f2bf(v.z); o.w = f2bf(v.w);
    ((ushort4*)out)[i] = o;
  }
}

// ---------------- fused convert: all 4 weights in one dispatch (grid-stride) ----------------
__global__ __launch_bounds__(256) void convert4(const float* __restrict__ s0, unsigned short* __restrict__ d0, int n0,
                                                const float* __restrict__ s1, unsigned short* __restrict__ d1, int n1,
                                                const float* __restrict__ s2, unsigned short* __restrict__ d2, int n2,
                                                const float* __restrict__ s3, unsigned short* __restrict__ d3, int n3) {
  const int tid = blockIdx.x * 256 + threadIdx.x;
  const int stride = gridDim.x * 256;
  for (int i = tid; i < n0; i += stride) {
    float4 v = ((const float4*)s0)[i];
    ushort4 o; o.x = f2bf(v.x); o.y = f2bf(v.y); o.z = f2bf(v.z); o.w = f2bf(v.w);
    ((ushort4*)d0)[i] = o;
  }
  for (int i = tid; i < n1; i += stride) {
    float4 v = ((const float4*)s1)[i];
    ushort4 o; o.x = f2bf(v.x); o.y = f2bf(v.y); o.z = f2bf(v.z); o.w = f2bf(v.w);
    ((ushort4*)d1)[i] = o;
  }
  for (int i = tid; i < n2; i += stride) {
    float4 v = ((const float4*)s2)[i];
    ushort4 o; o.x = f2bf(v.x); o.y = f2bf(v.y); o.z = f2bf(v.z); o.w = f2bf(v.w);
    ((ushort4*)d2)[i] = o;
  }
  for (int i = tid; i < n3; i += stride) {
    float4 v = ((const float4*)s3)[i];
    ushort4 o; o.x = f2bf(v.x); o.y = f2bf(v.y); o.z = f2bf(v.z); o.w = f2bf(v.w);
    ((ushort4*)d3)[i] = o;
  }
}

// ---------------- LayerNorm: fp32 [rows][1024] -> bf16 ----------------
__global__ __launch_bounds__(256) void ln_kernel(const float* __restrict__ x,
                                                 const float* __restrict__ w,
                                                 const float* __restrict__ b,
                                                 unsigned short* __restrict__ out) {
  int row = blockIdx.x, t = threadIdx.x;
  float4 v = ((const float4*)(x + (size_t)row * DM))[t];
  float s  = v.x + v.y + v.z + v.w;
  float sq = v.x*v.x + v.y*v.y + v.z*v.z + v.w*v.w;
  #pragma unroll
  for (int o = 32; o; o >>= 1) { s += __shfl_down(s, o); sq += __shfl_down(sq, o); }
  __shared__ float sh[8];
  if ((t & 63) == 0) { sh[t >> 6] = s; sh[4 + (t >> 6)] = sq; }
  __syncthreads();
  float S  = sh[0] + sh[1] + sh[2] + sh[3];
  float SQ = sh[4] + sh[5] + sh[6] + sh[7];
  float mu  = S * (1.0f / DM);
  float var = SQ * (1.0f / DM) - mu * mu;
  float rs  = rsqrtf(var + 1e-5f);
  float4 wv = ((const float4*)w)[t];
  float4 bv = ((const float4*)b)[t];
  ushort4 o;
  o.x = f2bf((v.x - mu) * rs * wv.x + bv.x);
  o.y = f2bf((v.y - mu) * rs * wv.y + bv.y);
  o.z = f2bf((v.z - mu) * rs * wv.z + bv.z);
  o.w = f2bf((v.w - mu) * rs * wv.w + bv.w);
  ((ushort4*)(out + (size_t)row * DM))[t] = o;
}

// ---------------- gemm8: 256x256 tile, 8 waves, minimum-2-phase (R15 best-known) ----------------
// For M%256==0, N%256==0, K%128==0. A:[M][lda], W:[N][ldb] bf16.
// Per K-tile: stage(t+1) FIRST (loads fly under this tile's MFMA block), then
// ds_read + 64 MFMA/wave (setprio), then ONE __syncthreads (drains vmcnt).
// K-tiles unrolled in pairs with literal buffer indices. XOR-swizzled LDS both sides.
// EPI 0: bf16(acc+bias); EPI 2: bf16(gelu_tanh(acc+bias))
template <int EPI>
__global__ __launch_bounds__(512) void gemm8(const unsigned short* __restrict__ A,
                                             const unsigned short* __restrict__ Bw,
                                             const float* __restrict__ bias,
                                             unsigned short* __restrict__ Cout,
                                             int M, int N, int K, int lda, int ldb) {
  __shared__ unsigned short As[2][256 * 64];   // 64 KB
  __shared__ unsigned short Bs[2][256 * 64];   // 64 KB
  const int t = threadIdx.x;
  const int l = t & 63, lr = l & 15, lg = l >> 4;
  const int wid = t >> 6, wm = wid >> 2, wn = wid & 3;   // 2 x 4 waves

  // T1: XCD-contiguous remap (bijective; totals here are %8==0)
  int bx = blockIdx.x, by = blockIdx.y;
  {
    const int gx = gridDim.x;
    const int total = gx * gridDim.y;
    if ((total & 7) == 0) {
      int lin = by * gx + bx;
      int lin2 = (lin & 7) * (total >> 3) + (lin >> 3);
      bx = lin2 % gx;
      by = lin2 / gx;
    }
  }
  const int m0 = by * 256, n0 = bx * 256;

  f32x4 acc[8][4];
  #pragma unroll
  for (int mi = 0; mi < 8; ++mi)
    #pragma unroll
    for (int ni = 0; ni < 4; ++ni) acc[mi][ni] = {0.f, 0.f, 0.f, 0.f};

  // staging: thread t covers row (t>>3) of each 64-row group, seg (t&7), XOR-preswizzled src
  const int rowt = t >> 3, sw = (t & 7) ^ (rowt & 7);
  const unsigned short* Ag = A  + (size_t)(m0 + rowt) * lda + sw * 8;
  const unsigned short* Bg = Bw + (size_t)(n0 + rowt) * ldb + sw * 8;
  const size_t r64A = (size_t)64 * lda;
  const size_t r64B = (size_t)64 * ldb;

  const int rs = lr & 7;
  const int segA = (lg ^ rs) * 8;        // k 0..31 half
  const int segB = ((lg + 4) ^ rs) * 8;  // k 32..63 half

  const int nt = K >> 6;

  auto stage = [&](int kt, int buf) {
    const int k0 = kt << 6;
    char* Ad = (char*)&As[buf][0] + t * 16;
    char* Bd = (char*)&Bs[buf][0] + t * 16;
    #pragma unroll
    for (int g = 0; g < 4; ++g) GLDS16(Ag + k0 + g * r64A, Ad + g * 8192);
    #pragma unroll
    for (int g = 0; g < 4; ++g) GLDS16(Bg + k0 + g * r64B, Bd + g * 8192);
  };

  auto compute = [&](const unsigned short* __restrict__ Ab,
                     const unsigned short* __restrict__ Bb) {
    short8 bfr[4][2];
    #pragma unroll
    for (int ni = 0; ni < 4; ++ni) {
      const int row = wn * 64 + ni * 16 + lr;
      bfr[ni][0] = *(const short8*)&Bb[row * 64 + segA];
      bfr[ni][1] = *(const short8*)&Bb[row * 64 + segB];
    }
    __builtin_amdgcn_s_setprio(1);
    #pragma unroll
    for (int mp = 0; mp < 4; ++mp) {   // mi-pairs to bound register liveness
      short8 af[2][2];
      #pragma unroll
      for (int q = 0; q < 2; ++q) {
        const int row = wm * 128 + (mp * 2 + q) * 16 + lr;
        af[q][0] = *(const short8*)&Ab[row * 64 + segA];
        af[q][1] = *(const short8*)&Ab[row * 64 + segB];
      }
      #pragma unroll
      for (int q = 0; q < 2; ++q)
        #pragma unroll
        for (int ni = 0; ni < 4; ++ni) {
          acc[mp * 2 + q][ni] = __builtin_amdgcn_mfma_f32_16x16x32_bf16(af[q][0], bfr[ni][0], acc[mp * 2 + q][ni], 0, 0, 0);
          acc[mp * 2 + q][ni] = __builtin_amdgcn_mfma_f32_16x16x32_bf16(af[q][1], bfr[ni][1], acc[mp * 2 + q][ni], 0, 0, 0);
        }
    }
    __builtin_amdgcn_s_setprio(0);
  };

  // prologue: tile 0 staged and drained (one exposed load, paid once)
  stage(0, 0);
  __syncthreads();

  for (int kt = 0; kt < nt; kt += 2) {
    if (kt + 1 < nt) stage(kt + 1, 1);
    compute(As[0], Bs[0]);
    __syncthreads();                       // drains stage(kt+1)
    if (kt + 2 < nt) stage(kt + 2, 0);
    compute(As[1], Bs[1]);
    __syncthreads();                       // drains stage(kt+2)
  }

  #pragma unroll
  for (int mi = 0; mi < 8; ++mi) {
    int row = m0 + wm * 128 + mi * 16 + lg * 4;
    #pragma unroll
    for (int ni = 0; ni < 4; ++ni) {
      int col = n0 + wn * 64 + ni * 16 + lr;
      float bv = bias[col];
      #pragma unroll
      for (int r = 0; r < 4; ++r) {
        float v = acc[mi][ni][r] + bv;
        size_t idx = (size_t)(row + r) * N + col;
        if (EPI == 0) {
          Cout[idx] = f2bf(v);
        } else {
          Cout[idx] = f2bf(gelu_tanh(v));
        }
      }
    }
  }
}

// ---------------- GEMM (2-phase): C[m][n] = A[m][:]·W[n][:] — small-N shapes ----------------
// Tile BM x 64, BK=64; 4 waves; XOR-swizzled LDS both sides (conflicts: 0, R10).
// EPI 0: bf16(acc+bias); EPI 1: f32 res+acc+bias; EPI 2: bf16(gelu_tanh(acc+bias));
// EPI 3: f32 Cout += acc (no bias; split-K accumulate pass)
template <int EPI, int BM>
__global__ __launch_bounds__(256) void gemm_bt(const unsigned short* __restrict__ A,
                                               const unsigned short* __restrict__ Bw,
                                               const float* __restrict__ bias,
                                               const float* __restrict__ res,
                                               void* __restrict__ Cout,
                                               int M, int N, int K, int lda, int ldb) {
  constexpr int MI   = BM / 32;
  constexpr int ABUF = BM * 64;
  __shared__ unsigned short As[2 * ABUF];
  __shared__ unsigned short Bs[2 * 64 * 64];
  const int t = threadIdx.x;
  const int l = t & 63, lr = l & 15, lg = l >> 4;
  const int w = t >> 6, wm = w >> 1, wn = w & 1;

  int bx = blockIdx.x, by = blockIdx.y;
  {
    const int gx = gridDim.x;
    const int total = gx * gridDim.y;
    if ((total & 7) == 0) {
      int lin = by * gx + bx;
      int lin2 = (lin & 7) * (total >> 3) + (lin >> 3);
      bx = lin2 % gx;
      by = lin2 / gx;
    }
  }
  const int m0 = by * BM, n0 = bx * 64;

  f32x4 acc[MI][2];
  #pragma unroll
  for (int mi = 0; mi < MI; ++mi)
    #pragma unroll
    for (int ni = 0; ni < 2; ++ni) acc[mi][ni] = {0.f, 0.f, 0.f, 0.f};

  const int rowt = t >> 3, sw = (t & 7) ^ (rowt & 7);
  const unsigned short* Ag = A  + (size_t)(m0 + rowt) * lda + sw * 8;
  const unsigned short* Bg = Bw + (size_t)(n0 + rowt) * ldb + sw * 8;
  char* AsB = (char*)As + t * 16;
  char* BsB = (char*)Bs + t * 16;
  const size_t r32A = (size_t)32 * lda;
  const size_t r32B = (size_t)32 * ldb;

  const int rs = lr & 7;
  const int segA = (lg ^ rs) * 8;
  const int segB = ((lg + 4) ^ rs) * 8;

  #pragma unroll
  for (int g = 0; g < MI; ++g) GLDS16(Ag + g * r32A, AsB + g * 4096);
  GLDS16(Bg,        BsB);
  GLDS16(Bg + r32B, BsB + 4096);

  int cur = 0;
  for (int k0 = 0; k0 < K; k0 += 64, cur ^= 1) {
    __syncthreads();
    const int kn = k0 + 64;
    if (kn < K) {
      char* An = AsB + (cur ^ 1) * (ABUF * 2);
      char* Bn = BsB + (cur ^ 1) * 8192;
      #pragma unroll
      for (int g = 0; g < MI; ++g) GLDS16(Ag + kn + g * r32A, An + g * 4096);
      GLDS16(Bg + kn,        Bn);
      GLDS16(Bg + kn + r32B, Bn + 4096);
    }
    const unsigned short* Ab = As + cur * ABUF;
    const unsigned short* Bb = Bs + cur * (64 * 64);
    short8 af[MI][2], bfr[2][2];
    #pragma unroll
    for (int mi = 0; mi < MI; ++mi) {
      const int row = wm * (BM / 2) + mi * 16 + lr;
      af[mi][0] = *(const short8*)&Ab[row * 64 + segA];
      af[mi][1] = *(const short8*)&Ab[row * 64 + segB];
    }
    #pragma unroll
    for (int ni = 0; ni < 2; ++ni) {
      const int row = wn * 32 + ni * 16 + lr;
      bfr[ni][0] = *(const short8*)&Bb[row * 64 + segA];
      bfr[ni][1] = *(const short8*)&Bb[row * 64 + segB];
    }
    #pragma unroll
    for (int mi = 0; mi < MI; ++mi)
      #pragma unroll
      for (int ni = 0; ni < 2; ++ni) {
        acc[mi][ni] = __builtin_amdgcn_mfma_f32_16x16x32_bf16(af[mi][0], bfr[ni][0], acc[mi][ni], 0, 0, 0);
        acc[mi][ni] = __builtin_amdgcn_mfma_f32_16x16x32_bf16(af[mi][1], bfr[ni][1], acc[mi][ni], 0, 0, 0);
      }
  }

  #pragma unroll
  for (int mi = 0; mi < MI; ++mi) {
    int row = m0 + wm * (BM / 2) + mi * 16 + lg * 4;
    #pragma unroll
    for (int ni = 0; ni < 2; ++ni) {
      int col = n0 + wn * 32 + ni * 16 + lr;
      float bv = (EPI == 3) ? 0.f : bias[col];
      #pragma unroll
      for (int r = 0; r < 4; ++r) {
        float v = acc[mi][ni][r] + bv;
        size_t idx = (size_t)(row + r) * N + col;
        if (EPI == 0) {
          ((unsigned short*)Cout)[idx] = f2bf(v);
        } else if (EPI == 1) {
          ((float*)Cout)[idx] = res[idx] + v;
        } else if (EPI == 2) {
          ((unsigned short*)Cout)[idx] = f2bf(gelu_tanh(v));
        } else {
          ((float*)Cout)[idx] += v;
        }
      }
    }
  }
}

// ---------------- V transpose: qkv[b][j][2048+h*64+d] -> vt[(b*16+h)*64+d][j] ----------------
__global__ __launch_bounds__(256) void vtrans_kernel(const unsigned short* __restrict__ qkv,
                                                     unsigned short* __restrict__ vt) {
  __shared__ unsigned short tile[64][72];
  int bh = blockIdx.y, b = bh >> 4, h = bh & 15;
  int j0 = blockIdx.x * 64, t = threadIdx.x;
  #pragma unroll
  for (int r = 0; r < 2; ++r) {
    int j = r * 32 + (t >> 3), d0 = (t & 7) * 8;
    short8 v = *(const short8*)(qkv + (size_t)(b * LL + j0 + j) * 3072 + 2048 + h * 64 + d0);
    #pragma unroll
    for (int e = 0; e < 8; ++e) tile[j][d0 + e] = (unsigned short)v[e];
  }
  __syncthreads();
  #pragma unroll
  for (int r = 0; r < 2; ++r) {
    int d = r * 32 + (t >> 3), j = (t & 7) * 8;
    short8 o;
    #pragma unroll
    for (int e = 0; e < 8; ++e) o[e] = (short)tile[j + e][d];
    *(short8*)(vt + (size_t)(bh * 64 + d) * LL + j0 + j) = o;
  }
}

// ---------------- Flash attention with prefix-decoder mask ----------------
// grid: (L/128, B*H), 8 waves x 512 threads; wave w owns q-rows i0+w*16 .. +15.
// allowed(i,j) = (j<m) | (i>=m & j<=i)
// SWAPPED QK^T; no-max softmax; row-sum via ones-column MFMA; dbuf K/V staging.
__global__ __launch_bounds__(512) void attn_kernel(const unsigned short* __restrict__ qkv,
                                                   const unsigned short* __restrict__ vt,
                                                   const int* __restrict__ prefix,
                                                   unsigned short* __restrict__ ctx) {
  __shared__ unsigned short Ks[2][64 * 64];
  __shared__ unsigned short Vs[2][64 * 64];
  __shared__ unsigned short Plds[8][16][72];
  const int t = threadIdx.x, w = t >> 6, l = t & 63, lr = l & 15, lg = l >> 4;
  const int bh = blockIdx.y, b = bh >> 4, h = bh & 15;
  const int ib = gridDim.x - 1 - blockIdx.x;
  const int i0 = ib * 128, iw = i0 + w * 16;
  const int m = *prefix;
  const float C = 0.125f * 1.44269504088896f;

  const int r0 = t >> 3, s0 = t & 7, swz = s0 ^ (r0 & 7);
  const unsigned short* Kg0 = qkv + (size_t)(b * LL + r0) * 3072 + DM + h * 64 + swz * 8;
  const unsigned short* Vg0 = vt + (size_t)(bh * 64 + r0) * LL + swz * 8;
  char* KdB = (char*)Ks + t * 16;
  char* VdB = (char*)Vs + t * 16;
  const int rs = lr & 7;
  const int segA = (lg ^ rs) * 8;
  const int segB = ((lg + 4) ^ rs) * 8;

  short8 qf[2];
  {
    const unsigned short* qrow = qkv + (size_t)(b * LL + iw + lr) * 3072 + h * 64;
    qf[0] = *(const short8*)(qrow + lg * 8);
    qf[1] = *(const short8*)(qrow + 32 + lg * 8);
  }
  short8 ones;
  #pragma unroll
  for (int e = 0; e < 8; ++e) ones[e] = (short)0x3F80;

  f32x4 Ot[4];
  #pragma unroll
  for (int dt = 0; dt < 4; ++dt) Ot[dt] = {0.f, 0.f, 0.f, 0.f};
  f32x4 Osum = {0.f, 0.f, 0.f, 0.f};

  const int jmax = (i0 + 128 <= m) ? m : (i0 + 128);
  const int nb = (jmax + 63) >> 6;
  const int i_abs = iw + lr;

  GLDS16(Kg0, KdB);
  GLDS16(Vg0, VdB);

  for (int c = 0; c < nb; ++c) {
    __syncthreads();
    if (c + 1 < nb) {
      const size_t jn = (size_t)(c + 1) * 64;
      const int pn = (c + 1) & 1;
      GLDS16(Kg0 + jn * 3072, KdB + pn * 8192);
      GLDS16(Vg0 + jn,        VdB + pn * 8192);
    }
    const int jt = c * 64, p = c & 1;

    f32x4 sc[4];
    #pragma unroll
    for (int nt = 0; nt < 4; ++nt) {
      sc[nt] = {0.f, 0.f, 0.f, 0.f};
      const int row = nt * 16 + lr;
      short8 kf0 = *(const short8*)&Ks[p][row * 64 + segA];
      short8 kf1 = *(const short8*)&Ks[p][row * 64 + segB];
      sc[nt] = __builtin_amdgcn_mfma_f32_16x16x32_bf16(kf0, qf[0], sc[nt], 0, 0, 0);
      sc[nt] = __builtin_amdgcn_mfma_f32_16x16x32_bf16(kf1, qf[1], sc[nt], 0, 0, 0);
    }
    const bool full = (jt + 64 <= m) || (iw >= m && jt + 64 <= iw + 1);
    #pragma unroll
    for (int nt = 0; nt < 4; ++nt) {
      float p0 = exp2_fast(sc[nt][0] * C);
      float p1 = exp2_fast(sc[nt][1] * C);
      float p2 = exp2_fast(sc[nt][2] * C);
      float p3 = exp2_fast(sc[nt][3] * C);
      if (!full) {
        const int jb = jt + nt * 16 + lg * 4;
        const bool causal_i = (i_abs >= m);
        p0 = ((jb + 0 < m) || (causal_i && jb + 0 <= i_abs)) ? p0 : 0.f;
        p1 = ((jb + 1 < m) || (causal_i && jb + 1 <= i_abs)) ? p1 : 0.f;
        p2 = ((jb + 2 < m) || (causal_i && jb + 2 <= i_abs)) ? p2 : 0.f;
        p3 = ((jb + 3 < m) || (causal_i && jb + 3 <= i_abs)) ? p3 : 0.f;
      }
      uint2 pk;
      pk.x = cvtpk_bf16(p0, p1);
      pk.y = cvtpk_bf16(p2, p3);
      *(uint2*)&Plds[w][lr][nt * 16 + lg * 4] = pk;
    }
    short8 paf0 = *(const short8*)&Plds[w][lr][lg * 8];
    short8 paf1 = *(const short8*)&Plds[w][lr][32 + lg * 8];
    #pragma unroll
    for (int dt = 0; dt < 4; ++dt) {
      const int row = dt * 16 + lr;
      short8 vf0 = *(const short8*)&Vs[p][row * 64 + segA];
      short8 vf1 = *(const short8*)&Vs[p][row * 64 + segB];
      Ot[dt] = __builtin_amdgcn_mfma_f32_16x16x32_bf16(paf0, vf0, Ot[dt], 0, 0, 0);
      Ot[dt] = __builtin_amdgcn_mfma_f32_16x16x32_bf16(paf1, vf1, Ot[dt], 0, 0, 0);
    }
    Osum = __builtin_amdgcn_mfma_f32_16x16x32_bf16(paf0, ones, Osum, 0, 0, 0);
    Osum = __builtin_amdgcn_mfma_f32_16x16x32_bf16(paf1, ones, Osum, 0, 0, 0);
  }
  #pragma unroll
  for (int r = 0; r < 4; ++r) {
    float inv = 1.0f / Osum[r];
    size_t row = (size_t)(b * LL + iw + lg * 4 + r);
    #pragma unroll
    for (int dt = 0; dt < 4; ++dt)
      ctx[row * DM + h * 64 + dt * 16 + lr] = f2bf(Ot[dt][r] * inv);
  }
}

// ---------------- launch ----------------
// Layouts (lifetime-disjoint aliases):
//   base (56 MiB): slab[0,8) | x2[8,24) fp32, vt alias [8,16) | wslab[24,32) | qkv[32,56);
//                  after attn: wfc2[32,40) + ffh[40,56)
//   big (>=72 MiB): ffmid[40,72) -> single-pass fc1/fc2
//   wd (>=80 MiB): ALL weights disjoint + ONE fused convert at t=0:
//       w_in[24,30) w_out[30,32) w_fc1[64,72) w_fc2[72,80); ffmid[32,64) (over dead qkv)
extern "C" void kernel_launch(void* const* d_in, const int* in_sizes, int n_in,
                              void* d_out, int out_size, void* d_ws, size_t ws_size,
                              hipStream_t stream) {
  const float* x        = (const float*)d_in[0];
  const float* ln1_w    = (const float*)d_in[1];
  const float* ln1_b    = (const float*)d_in[2];
  const float* in_proj_w= (const float*)d_in[3];
  const float* in_proj_b= (const float*)d_in[4];
  const float* out_w    = (const float*)d_in[5];
  const float* out_b    = (const float*)d_in[6];
  const float* ln2_w    = (const float*)d_in[7];
  const float* ln2_b    = (const float*)d_in[8];
  const float* fc1_w    = (const float*)d_in[9];
  const float* fc1_b    = (const float*)d_in[10];
  const float* fc2_w    = (const float*)d_in[11];
  const float* fc2_b    = (const float*)d_in[12];
  const int*   prefix   = (const int*)d_in[13];
  float* outp = (float*)d_out;

  char* ws = (char*)d_ws;
  unsigned short* slab  = (unsigned short*)ws;                          // [0,8)
  float*          x2    = (float*)(ws + ((size_t)8 << 20));             // [8,24)
  unsigned short* vtb   = (unsigned short*)(ws + ((size_t)8 << 20));    // [8,16) alias
  unsigned short* wslab = (unsigned short*)(ws + ((size_t)24 << 20));   // [24,32)
  unsigned short* qkv   = (unsigned short*)(ws + ((size_t)32 << 20));   // [32,56)
  unsigned short* wfc2  = (unsigned short*)(ws + ((size_t)32 << 20));   // [32,40) alias
  unsigned short* ffh   = (unsigned short*)(ws + ((size_t)40 << 20));   // [40,56) alias
  const bool big = ws_size >= ((size_t)72 << 20);
  const bool wd  = ws_size >= ((size_t)80 << 20);

  // wd layout pointers
  unsigned short* w_in  = (unsigned short*)(ws + ((size_t)24 << 20));   // [24,30)
  unsigned short* w_out = (unsigned short*)(ws + ((size_t)30 << 20));   // [30,32)
  unsigned short* w_fc1 = (unsigned short*)(ws + ((size_t)64 << 20));   // [64,72)
  unsigned short* w_fc2 = (unsigned short*)(ws + ((size_t)72 << 20));   // [72,80)
  unsigned short* ffm32 = (unsigned short*)(ws + ((size_t)32 << 20));   // [32,64)

  // --- weight conversion ---
  if (wd) {
    convert4<<<1024, 256, 0, stream>>>(in_proj_w, w_in, 3072 * 1024 / 4,
                                       out_w, w_out, 1024 * 1024 / 4,
                                       fc1_w, w_fc1, 4096 * 1024 / 4,
                                       fc2_w, w_fc2, 1024 * 4096 / 4);
  } else {
    convert_f32_bf16<<<3072, 256, 0, stream>>>(in_proj_w, wslab, 3072 * 1024 / 4);
  }

  // --- attention half ---
  ln_kernel<<<MM, 256, 0, stream>>>(x, ln1_w, ln1_b, slab);
  gemm8<0><<<dim3(3072 / 256, MM / 256), 512, 0, stream>>>(slab, wd ? w_in : wslab, in_proj_b, qkv, MM, 3072, 1024, 1024, 1024);
  vtrans_kernel<<<dim3(LL / 64, BB * NH), 256, 0, stream>>>(qkv, vtb);
  attn_kernel<<<dim3(LL / 128, BB * NH), 512, 0, stream>>>(qkv, vtb, prefix, slab);
  if (!wd) convert_f32_bf16<<<1024, 256, 0, stream>>>(out_w, wslab, 1024 * 1024 / 4);
  gemm_bt<1, 64><<<dim3(1024 / 64, MM / 64), 256, 0, stream>>>(slab, wd ? w_out : wslab, out_b, x, x2, MM, 1024, 1024, 1024, 1024);

  // --- FFN ---
  ln_kernel<<<MM, 256, 0, stream>>>(x2, ln2_w, ln2_b, slab);
  if (wd) {
    gemm8<2><<<dim3(4096 / 256, MM / 256), 512, 0, stream>>>(slab, w_fc1, fc1_b, ffm32, MM, 4096, 1024, 1024, 1024);
    gemm_bt<1, 64><<<dim3(1024 / 64, MM / 64), 256, 0, stream>>>(ffm32, w_fc2, fc2_b, x2, outp, MM, 1024, 4096, 4096, 4096);
  } else {
    convert_f32_bf16<<<4096, 256, 0, stream>>>(fc1_w, wslab, 4096 * 1024 / 4);
    convert_f32_bf16<<<4096, 256, 0, stream>>>(fc2_w, wfc2, 1024 * 4096 / 4);  // qkv dead
    if (big) {
      unsigned short* ffmid = (unsigned short*)(ws + ((size_t)40 << 20));
      gemm8<2><<<dim3(4096 / 256, MM / 256), 512, 0, stream>>>(slab, wslab, fc1_b, ffmid, MM, 4096, 1024, 1024, 1024);
      gemm_bt<1, 64><<<dim3(1024 / 64, MM / 64), 256, 0, stream>>>(ffmid, wfc2, fc2_b, x2, outp, MM, 1024, 4096, 4096, 4096);
    } else {
      gemm_bt<2, 128><<<dim3(2048 / 64, MM / 128), 256, 0, stream>>>(slab, wslab, fc1_b, nullptr, ffh, MM, 2048, 1024, 1024, 1024);
      gemm_bt<1, 64><<<dim3(1024 / 64, MM / 64), 256, 0, stream>>>(ffh, wfc2, fc2_b, x2, outp, MM, 1024, 2048, 2048, 4096);
      gemm_bt<2, 128><<<dim3(2048 / 64, MM / 128), 256, 0, stream>>>(slab, wslab + (size_t)2048 * 1024, fc1_b + 2048, nullptr, ffh, MM, 2048, 1024, 1024, 1024);
      gemm_bt<3, 64><<<dim3(1024 / 64, MM / 64), 256, 0, stream>>>(ffh, wfc2 + 2048, nullptr, nullptr, outp, MM, 1024, 2048, 2048, 4096);
    }
  }
}

// Round 18
// 221.166 us; speedup vs baseline: 1.2063x; 1.0084x over previous
//
#include <hip/hip_runtime.h>
#include <cstdint>
#include <cstddef>

// Problem constants (PrefixDecoderBlock): B=2, L=2048, d_model=1024, H=16, hd=64, d_ff=4096
#define DM   1024
#define NH   16
#define HD   64
#define DFF  4096
#define BB   2
#define LL   2048
#define MM   (BB*LL)   // 4096 rows total

using short8 = __attribute__((ext_vector_type(8))) short;   // 8 bf16 (4 VGPRs) — MFMA A/B frag
using f32x4  = __attribute__((ext_vector_type(4))) float;   // MFMA C/D frag

// RNE float -> bf16
__device__ __forceinline__ unsigned short f2bf(float f) {
  union { float f; uint32_t u; } v; v.f = f;
  uint32_t u = v.u;
  uint32_t r = (u + 0x7fffu + ((u >> 16) & 1u)) >> 16;
  return (unsigned short)r;
}

// pack 2 f32 -> 2 bf16 (RNE): lo=a, hi=b
__device__ __forceinline__ uint32_t cvtpk_bf16(float a, float b) {
  uint32_t r;
  asm("v_cvt_pk_bf16_f32 %0, %1, %2" : "=v"(r) : "v"(a), "v"(b));
  return r;
}

// raw 2^x (v_exp_f32)
__device__ __forceinline__ float exp2_fast(float x) {
  float r;
  asm("v_exp_f32 %0, %1" : "=v"(r) : "v"(x));
  return r;
}

// raw 1/x (v_rcp_f32, approx — fine for gelu)
__device__ __forceinline__ float rcp_fast(float x) {
  float r;
  asm("v_rcp_f32 %0, %1" : "=v"(r) : "v"(x));
  return r;
}

__device__ __forceinline__ float gelu_tanh(float v) {
  float y = v * (0.7978845608028654f + 0.035677408136300125f * v * v);
  float e = exp2_fast(y * 2.885390081777927f);          // e^(2y)
  float tnh = 1.0f - 2.0f * rcp_fast(1.0f + e);
  return 0.5f * v * (1.0f + tnh);
}

#define GLDS16(gp, lp) \
  __builtin_amdgcn_global_load_lds((const __attribute__((address_space(1))) uint32_t*)(gp), \
                                   (__attribute__((address_space(3))) uint32_t*)(lp), 16, 0, 0)

__device__ __forceinline__ void ln_row_body(const float* __restrict__ x,
                                            const float* __restrict__ w,
                                            const float* __restrict__ b,
                                            unsigned short* __restrict__ out,
                                            int row, int t) {
  float4 v = ((const float4*)(x + (size_t)row * DM))[t];
  float s  = v.x + v.y + v.z + v.w;
  float sq = v.x*v.x + v.y*v.y + v.z*v.z + v.w*v.w;
  #pragma unroll
  for (int o = 32; o; o >>= 1) { s += __shfl_down(s, o); sq += __shfl_down(sq, o); }
  __shared__ float sh[8];
  if ((t & 63) == 0) { sh[t >> 6] = s; sh[4 + (t >> 6)] = sq; }
  __syncthreads();
  float S  = sh[0] + sh[1] + sh[2] + sh[3];
  float SQ = sh[4] + sh[5] + sh[6] + sh[7];
  float mu  = S * (1.0f / DM);
  float var = SQ * (1.0f / DM) - mu * mu;
  float rs  = rsqrtf(var + 1e-5f);
  float4 wv = ((const float4*)w)[t];
  float4 bv = ((const float4*)b)[t];
  ushort4 o;
  o.x = f2bf((v.x - mu) * rs * wv.x + bv.x);
  o.y = f2bf((v.y - mu) * rs * wv.y + bv.y);
  o.z = f2bf((v.z - mu) * rs * wv.z + bv.z);
  o.w = f2bf((v.w - mu) * rs * wv.w + bv.w);
  ((ushort4*)(out + (size_t)row * DM))[t] = o;
}

// ---------------- elementwise fp32 -> bf16 convert (weights) ----------------
__global__ __launch_bounds__(256) void convert_f32_bf16(const float* __restrict__ in,
                                                        unsigned short* __restrict__ out, int n4) {
  int i = blockIdx.x * 256 + threadIdx.x;
  if (i < n4) {
    float4 v = ((const float4*)in)[i];
    ushort4 o;
    o.x = f2bf(v.x); o.y = f2bf(v.y); o.z = f2bf(v.z); o.w = f2bf(v.w);
    ((ushort4*)out)[i] = o;
  }
}

// ---------------- prep: LN1 (blocks < MM) + all-4 weight converts (rest) ----------------
__global__ __launch_bounds__(256) void prep_kernel(const float* __restrict__ x,
                                                   const float* __restrict__ ln1_w,
                                                   const float* __restrict__ ln1_b,
                                                   unsigned short* __restrict__ h1,
                                                   const float* __restrict__ s0, unsigned short* __restrict__ d0, int n0,
                                                   const float* __restrict__ s1, unsigned short* __restrict__ d1, int n1,
                                                   const float* __restrict__ s2, unsigned short* __restrict__ d2, int n2,
                                                   const float* __restrict__ s3, unsigned short* __restrict__ d3, int n3) {
  if (blockIdx.x < MM) {
    ln_row_body(x, ln1_w, ln1_b, h1, blockIdx.x, threadIdx.x);
    return;
  }
  const int cb = blockIdx.x - MM;
  const int tid = cb * 256 + threadIdx.x;
  const int stride = (gridDim.x - MM) * 256;
  for (int i = tid; i < n0; i += stride) {
    float4 v = ((const float4*)s0)[i];
    ushort4 o; o.x = f2bf(v.x); o.y = f2bf(v.y); o.z = f2bf(v.z); o.w = f2bf(v.w);
    ((ushort4*)d0)[i] = o;
  }
  for (int i = tid; i < n1; i += stride) {
    float4 v = ((const float4*)s1)[i];
    ushort4 o; o.x = f2bf(v.x); o.y = f2bf(v.y); o.z = f2bf(v.z); o.w = f2bf(v.w);
    ((ushort4*)d1)[i] = o;
  }
  for (int i = tid; i < n2; i += stride) {
    float4 v = ((const float4*)s2)[i];
    ushort4 o; o.x = f2bf(v.x); o.y = f2bf(v.y); o.z = f2bf(v.z); o.w = f2bf(v.w);
    ((ushort4*)d2)[i] = o;
  }
  for (int i = tid; i < n3; i += stride) {
    float4 v = ((const float4*)s3)[i];
    ushort4 o; o.x = f2bf(v.x); o.y = f2bf(v.y); o.z = f2bf(v.z); o.w = f2bf(v.w);
    ((ushort4*)d3)[i] = o;
  }
}

// ---------------- LayerNorm: fp32 [rows][1024] -> bf16 ----------------
__global__ __launch_bounds__(256) void ln_kernel(const float* __restrict__ x,
                                                 const float* __restrict__ w,
                                                 const float* __restrict__ b,
                                                 unsigned short* __restrict__ out) {
  ln_row_body(x, w, b, out, blockIdx.x, threadIdx.x);
}

// ---------------- gemm8: 256x256 tile, 8 waves, minimum-2-phase (R15/R17 best-known) ----------------
// For M%256==0, N%256==0, K%128==0. A:[M][lda], W:[N][ldb] bf16.
// Per K-tile: stage(t+1) FIRST (loads fly under this tile's MFMA block), then
// ds_read + 64 MFMA/wave (setprio), then ONE __syncthreads (drains vmcnt).
// XOR-swizzled LDS both sides (0 bank conflicts, R10-verified).
// EPI 0: bf16(acc+bias); EPI 2: bf16(gelu_tanh(acc+bias))
// VT=1 (qkv only): V column-blocks (n0 >= 2048, block-uniform) write the
// TRANSPOSED value directly to vt[(b*16+h)*64+d][j] as packed 8B stores and
// skip the qkv store (attn reads V only via vt). Fuses away the vtrans kernel.
template <int EPI, int VT>
__global__ __launch_bounds__(512) void gemm8(const unsigned short* __restrict__ A,
                                             const unsigned short* __restrict__ Bw,
                                             const float* __restrict__ bias,
                                             unsigned short* __restrict__ Cout,
                                             unsigned short* __restrict__ vt,
                                             int M, int N, int K, int lda, int ldb) {
  __shared__ unsigned short As[2][256 * 64];   // 64 KB
  __shared__ unsigned short Bs[2][256 * 64];   // 64 KB
  const int t = threadIdx.x;
  const int l = t & 63, lr = l & 15, lg = l >> 4;
  const int wid = t >> 6, wm = wid >> 2, wn = wid & 3;   // 2 x 4 waves

  // T1: XCD-contiguous remap (bijective; totals here are %8==0)
  int bx = blockIdx.x, by = blockIdx.y;
  {
    const int gx = gridDim.x;
    const int total = gx * gridDim.y;
    if ((total & 7) == 0) {
      int lin = by * gx + bx;
      int lin2 = (lin & 7) * (total >> 3) + (lin >> 3);
      bx = lin2 % gx;
      by = lin2 / gx;
    }
  }
  const int m0 = by * 256, n0 = bx * 256;

  f32x4 acc[8][4];
  #pragma unroll
  for (int mi = 0; mi < 8; ++mi)
    #pragma unroll
    for (int ni = 0; ni < 4; ++ni) acc[mi][ni] = {0.f, 0.f, 0.f, 0.f};

  // staging: thread t covers row (t>>3) of each 64-row group, seg (t&7), XOR-preswizzled src
  const int rowt = t >> 3, sw = (t & 7) ^ (rowt & 7);
  const unsigned short* Ag = A  + (size_t)(m0 + rowt) * lda + sw * 8;
  const unsigned short* Bg = Bw + (size_t)(n0 + rowt) * ldb + sw * 8;
  const size_t r64A = (size_t)64 * lda;
  const size_t r64B = (size_t)64 * ldb;

  const int rs = lr & 7;
  const int segA = (lg ^ rs) * 8;        // k 0..31 half
  const int segB = ((lg + 4) ^ rs) * 8;  // k 32..63 half

  const int nt = K >> 6;

  auto stage = [&](int kt, int buf) {
    const int k0 = kt << 6;
    char* Ad = (char*)&As[buf][0] + t * 16;
    char* Bd = (char*)&Bs[buf][0] + t * 16;
    #pragma unroll
    for (int g = 0; g < 4; ++g) GLDS16(Ag + k0 + g * r64A, Ad + g * 8192);
    #pragma unroll
    for (int g = 0; g < 4; ++g) GLDS16(Bg + k0 + g * r64B, Bd + g * 8192);
  };

  auto compute = [&](const unsigned short* __restrict__ Ab,
                     const unsigned short* __restrict__ Bb) {
    short8 bfr[4][2];
    #pragma unroll
    for (int ni = 0; ni < 4; ++ni) {
      const int row = wn * 64 + ni * 16 + lr;
      bfr[ni][0] = *(const short8*)&Bb[row * 64 + segA];
      bfr[ni][1] = *(const short8*)&Bb[row * 64 + segB];
    }
    __builtin_amdgcn_s_setprio(1);
    #pragma unroll
    for (int mp = 0; mp < 4; ++mp) {   // mi-pairs to bound register liveness
      short8 af[2][2];
      #pragma unroll
      for (int q = 0; q < 2; ++q) {
        const int row = wm * 128 + (mp * 2 + q) * 16 + lr;
        af[q][0] = *(const short8*)&Ab[row * 64 + segA];
        af[q][1] = *(const short8*)&Ab[row * 64 + segB];
      }
      #pragma unroll
      for (int q = 0; q < 2; ++q)
        #pragma unroll
        for (int ni = 0; ni < 4; ++ni) {
          acc[mp * 2 + q][ni] = __builtin_amdgcn_mfma_f32_16x16x32_bf16(af[q][0], bfr[ni][0], acc[mp * 2 + q][ni], 0, 0, 0);
          acc[mp * 2 + q][ni] = __builtin_amdgcn_mfma_f32_16x16x32_bf16(af[q][1], bfr[ni][1], acc[mp * 2 + q][ni], 0, 0, 0);
        }
    }
    __builtin_amdgcn_s_setprio(0);
  };

  // prologue: tile 0 staged and drained (one exposed load, paid once)
  stage(0, 0);
  __syncthreads();

  for (int kt = 0; kt < nt; kt += 2) {
    if (kt + 1 < nt) stage(kt + 1, 1);
    compute(As[0], Bs[0]);
    __syncthreads();                       // drains stage(kt+1)
    if (kt + 2 < nt) stage(kt + 2, 0);
    compute(As[1], Bs[1]);
    __syncthreads();                       // drains stage(kt+2)
  }

  if (VT && n0 >= 2 * DM) {
    // V block: write transposed to vt (rows of vt = b*1024 + h*64+d, cols = j)
    #pragma unroll
    for (int mi = 0; mi < 8; ++mi) {
      int row = m0 + wm * 128 + mi * 16 + lg * 4;   // = b*LL + j
      int b = row >> 11, j = row & (LL - 1);
      #pragma unroll
      for (int ni = 0; ni < 4; ++ni) {
        int col = n0 + wn * 64 + ni * 16 + lr;
        int hd_ = col - 2 * DM;                      // h*64 + d
        float bv = bias[col];
        uint2 pk;
        pk.x = cvtpk_bf16(acc[mi][ni][0] + bv, acc[mi][ni][1] + bv);
        pk.y = cvtpk_bf16(acc[mi][ni][2] + bv, acc[mi][ni][3] + bv);
        *(uint2*)&vt[(size_t)(b * 1024 + hd_) * LL + j] = pk;
      }
    }
    return;
  }

  #pragma unroll
  for (int mi = 0; mi < 8; ++mi) {
    int row = m0 + wm * 128 + mi * 16 + lg * 4;
    #pragma unroll
    for (int ni = 0; ni < 4; ++ni) {
      int col = n0 + wn * 64 + ni * 16 + lr;
      float bv = bias[col];
      #pragma unroll
      for (int r = 0; r < 4; ++r) {
        float v = acc[mi][ni][r] + bv;
        size_t idx = (size_t)(row + r) * N + col;
        if (EPI == 0) {
          Cout[idx] = f2bf(v);
        } else {
          Cout[idx] = f2bf(gelu_tanh(v));
        }
      }
    }
  }
}

// ---------------- GEMM (2-phase): C[m][n] = A[m][:]·W[n][:] — small-N shapes ----------------
// Tile BM x 64, BK=64; 4 waves; XOR-swizzled LDS both sides (conflicts: 0, R10).
// EPI 0: bf16(acc+bias); EPI 1: f32 res+acc+bias; EPI 2: bf16(gelu_tanh(acc+bias));
// EPI 3: f32 Cout += acc (no bias; split-K accumulate pass)
template <int EPI, int BM>
__global__ __launch_bounds__(256) void gemm_bt(const unsigned short* __restrict__ A,
                                               const unsigned short* __restrict__ Bw,
                                               const float* __restrict__ bias,
                                               const float* __restrict__ res,
                                               void* __restrict__ Cout,
                                               int M, int N, int K, int lda, int ldb) {
  constexpr int MI   = BM / 32;
  constexpr int ABUF = BM * 64;
  __shared__ unsigned short As[2 * ABUF];
  __shared__ unsigned short Bs[2 * 64 * 64];
  const int t = threadIdx.x;
  const int l = t & 63, lr = l & 15, lg = l >> 4;
  const int w = t >> 6, wm = w >> 1, wn = w & 1;

  int bx = blockIdx.x, by = blockIdx.y;
  {
    const int gx = gridDim.x;
    const int total = gx * gridDim.y;
    if ((total & 7) == 0) {
      int lin = by * gx + bx;
      int lin2 = (lin & 7) * (total >> 3) + (lin >> 3);
      bx = lin2 % gx;
      by = lin2 / gx;
    }
  }
  const int m0 = by * BM, n0 = bx * 64;

  f32x4 acc[MI][2];
  #pragma unroll
  for (int mi = 0; mi < MI; ++mi)
    #pragma unroll
    for (int ni = 0; ni < 2; ++ni) acc[mi][ni] = {0.f, 0.f, 0.f, 0.f};

  const int rowt = t >> 3, sw = (t & 7) ^ (rowt & 7);
  const unsigned short* Ag = A  + (size_t)(m0 + rowt) * lda + sw * 8;
  const unsigned short* Bg = Bw + (size_t)(n0 + rowt) * ldb + sw * 8;
  char* AsB = (char*)As + t * 16;
  char* BsB = (char*)Bs + t * 16;
  const size_t r32A = (size_t)32 * lda;
  const size_t r32B = (size_t)32 * ldb;

  const int rs = lr & 7;
  const int segA = (lg ^ rs) * 8;
  const int segB = ((lg + 4) ^ rs) * 8;

  #pragma unroll
  for (int g = 0; g < MI; ++g) GLDS16(Ag + g * r32A, AsB + g * 4096);
  GLDS16(Bg,        BsB);
  GLDS16(Bg + r32B, BsB + 4096);

  int cur = 0;
  for (int k0 = 0; k0 < K; k0 += 64, cur ^= 1) {
    __syncthreads();
    const int kn = k0 + 64;
    if (kn < K) {
      char* An = AsB + (cur ^ 1) * (ABUF * 2);
      char* Bn = BsB + (cur ^ 1) * 8192;
      #pragma unroll
      for (int g = 0; g < MI; ++g) GLDS16(Ag + kn + g * r32A, An + g * 4096);
      GLDS16(Bg + kn,        Bn);
      GLDS16(Bg + kn + r32B, Bn + 4096);
    }
    const unsigned short* Ab = As + cur * ABUF;
    const unsigned short* Bb = Bs + cur * (64 * 64);
    short8 af[MI][2], bfr[2][2];
    #pragma unroll
    for (int mi = 0; mi < MI; ++mi) {
      const int row = wm * (BM / 2) + mi * 16 + lr;
      af[mi][0] = *(const short8*)&Ab[row * 64 + segA];
      af[mi][1] = *(const short8*)&Ab[row * 64 + segB];
    }
    #pragma unroll
    for (int ni = 0; ni < 2; ++ni) {
      const int row = wn * 32 + ni * 16 + lr;
      bfr[ni][0] = *(const short8*)&Bb[row * 64 + segA];
      bfr[ni][1] = *(const short8*)&Bb[row * 64 + segB];
    }
    #pragma unroll
    for (int mi = 0; mi < MI; ++mi)
      #pragma unroll
      for (int ni = 0; ni < 2; ++ni) {
        acc[mi][ni] = __builtin_amdgcn_mfma_f32_16x16x32_bf16(af[mi][0], bfr[ni][0], acc[mi][ni], 0, 0, 0);
        acc[mi][ni] = __builtin_amdgcn_mfma_f32_16x16x32_bf16(af[mi][1], bfr[ni][1], acc[mi][ni], 0, 0, 0);
      }
  }

  #pragma unroll
  for (int mi = 0; mi < MI; ++mi) {
    int row = m0 + wm * (BM / 2) + mi * 16 + lg * 4;
    #pragma unroll
    for (int ni = 0; ni < 2; ++ni) {
      int col = n0 + wn * 32 + ni * 16 + lr;
      float bv = (EPI == 3) ? 0.f : bias[col];
      #pragma unroll
      for (int r = 0; r < 4; ++r) {
        float v = acc[mi][ni][r] + bv;
        size_t idx = (size_t)(row + r) * N + col;
        if (EPI == 0) {
          ((unsigned short*)Cout)[idx] = f2bf(v);
        } else if (EPI == 1) {
          ((float*)Cout)[idx] = res[idx] + v;
        } else if (EPI == 2) {
          ((unsigned short*)Cout)[idx] = f2bf(gelu_tanh(v));
        } else {
          ((float*)Cout)[idx] += v;
        }
      }
    }
  }
}

// ---------------- Flash attention with prefix-decoder mask ----------------
// grid: (L/128, B*H), 8 waves x 512 threads; wave w owns q-rows i0+w*16 .. +15.
// allowed(i,j) = (j<m) | (i>=m & j<=i)
// SWAPPED QK^T; no-max softmax; row-sum via ones-column MFMA; dbuf K/V staging.
__global__ __launch_bounds__(512) void attn_kernel(const unsigned short* __restrict__ qkv,
                                                   const unsigned short* __restrict__ vt,
                                                   const int* __restrict__ prefix,
                                                   unsigned short* __restrict__ ctx) {
  __shared__ unsigned short Ks[2][64 * 64];
  __shared__ unsigned short Vs[2][64 * 64];
  __shared__ unsigned short Plds[8][16][72];
  const int t = threadIdx.x, w = t >> 6, l = t & 63, lr = l & 15, lg = l >> 4;
  const int bh = blockIdx.y, b = bh >> 4, h = bh & 15;
  const int ib = gridDim.x - 1 - blockIdx.x;
  const int i0 = ib * 128, iw = i0 + w * 16;
  const int m = *prefix;
  const float C = 0.125f * 1.44269504088896f;

  const int r0 = t >> 3, s0 = t & 7, swz = s0 ^ (r0 & 7);
  const unsigned short* Kg0 = qkv + (size_t)(b * LL + r0) * 3072 + DM + h * 64 + swz * 8;
  const unsigned short* Vg0 = vt + (size_t)(bh * 64 + r0) * LL + swz * 8;
  char* KdB = (char*)Ks + t * 16;
  char* VdB = (char*)Vs + t * 16;
  const int rs = lr & 7;
  const int segA = (lg ^ rs) * 8;
  const int segB = ((lg + 4) ^ rs) * 8;

  short8 qf[2];
  {
    const unsigned short* qrow = qkv + (size_t)(b * LL + iw + lr) * 3072 + h * 64;
    qf[0] = *(const short8*)(qrow + lg * 8);
    qf[1] = *(const short8*)(qrow + 32 + lg * 8);
  }
  short8 ones;
  #pragma unroll
  for (int e = 0; e < 8; ++e) ones[e] = (short)0x3F80;

  f32x4 Ot[4];
  #pragma unroll
  for (int dt = 0; dt < 4; ++dt) Ot[dt] = {0.f, 0.f, 0.f, 0.f};
  f32x4 Osum = {0.f, 0.f, 0.f, 0.f};

  const int jmax = (i0 + 128 <= m) ? m : (i0 + 128);
  const int nb = (jmax + 63) >> 6;
  const int i_abs = iw + lr;

  GLDS16(Kg0, KdB);
  GLDS16(Vg0, VdB);

  for (int c = 0; c < nb; ++c) {
    __syncthreads();
    if (c + 1 < nb) {
      const size_t jn = (size_t)(c + 1) * 64;
      const int pn = (c + 1) & 1;
      GLDS16(Kg0 + jn * 3072, KdB + pn * 8192);
      GLDS16(Vg0 + jn,        VdB + pn * 8192);
    }
    const int jt = c * 64, p = c & 1;

    f32x4 sc[4];
    #pragma unroll
    for (int nt = 0; nt < 4; ++nt) {
      sc[nt] = {0.f, 0.f, 0.f, 0.f};
      const int row = nt * 16 + lr;
      short8 kf0 = *(const short8*)&Ks[p][row * 64 + segA];
      short8 kf1 = *(const short8*)&Ks[p][row * 64 + segB];
      sc[nt] = __builtin_amdgcn_mfma_f32_16x16x32_bf16(kf0, qf[0], sc[nt], 0, 0, 0);
      sc[nt] = __builtin_amdgcn_mfma_f32_16x16x32_bf16(kf1, qf[1], sc[nt], 0, 0, 0);
    }
    const bool full = (jt + 64 <= m) || (iw >= m && jt + 64 <= iw + 1);
    #pragma unroll
    for (int nt = 0; nt < 4; ++nt) {
      float p0 = exp2_fast(sc[nt][0] * C);
      float p1 = exp2_fast(sc[nt][1] * C);
      float p2 = exp2_fast(sc[nt][2] * C);
      float p3 = exp2_fast(sc[nt][3] * C);
      if (!full) {
        const int jb = jt + nt * 16 + lg * 4;
        const bool causal_i = (i_abs >= m);
        p0 = ((jb + 0 < m) || (causal_i && jb + 0 <= i_abs)) ? p0 : 0.f;
        p1 = ((jb + 1 < m) || (causal_i && jb + 1 <= i_abs)) ? p1 : 0.f;
        p2 = ((jb + 2 < m) || (causal_i && jb + 2 <= i_abs)) ? p2 : 0.f;
        p3 = ((jb + 3 < m) || (causal_i && jb + 3 <= i_abs)) ? p3 : 0.f;
      }
      uint2 pk;
      pk.x = cvtpk_bf16(p0, p1);
      pk.y = cvtpk_bf16(p2, p3);
      *(uint2*)&Plds[w][lr][nt * 16 + lg * 4] = pk;
    }
    short8 paf0 = *(const short8*)&Plds[w][lr][lg * 8];
    short8 paf1 = *(const short8*)&Plds[w][lr][32 + lg * 8];
    #pragma unroll
    for (int dt = 0; dt < 4; ++dt) {
      const int row = dt * 16 + lr;
      short8 vf0 = *(const short8*)&Vs[p][row * 64 + segA];
      short8 vf1 = *(const short8*)&Vs[p][row * 64 + segB];
      Ot[dt] = __builtin_amdgcn_mfma_f32_16x16x32_bf16(paf0, vf0, Ot[dt], 0, 0, 0);
      Ot[dt] = __builtin_amdgcn_mfma_f32_16x16x32_bf16(paf1, vf1, Ot[dt], 0, 0, 0);
    }
    Osum = __builtin_amdgcn_mfma_f32_16x16x32_bf16(paf0, ones, Osum, 0, 0, 0);
    Osum = __builtin_amdgcn_mfma_f32_16x16x32_bf16(paf1, ones, Osum, 0, 0, 0);
  }
  #pragma unroll
  for (int r = 0; r < 4; ++r) {
    float inv = 1.0f / Osum[r];
    size_t row = (size_t)(b * LL + iw + lg * 4 + r);
    #pragma unroll
    for (int dt = 0; dt < 4; ++dt)
      ctx[row * DM + h * 64 + dt * 16 + lr] = f2bf(Ot[dt][r] * inv);
  }
}

// ---------------- launch ----------------
// Layouts (lifetime-disjoint aliases):
//   base (56 MiB): slab[0,8) | x2[8,24) fp32, vt alias [8,16) | wslab[24,32) | qkv[32,56);
//                  after attn: wfc2[32,40) + ffh[40,56)
//   big (>=72 MiB): ffmid[40,72) -> single-pass fc1/fc2
//   wd (>=80 MiB): ALL weights disjoint + ONE fused prep (LN1 + 4 converts):
//       w_in[24,30) w_out[30,32) w_fc1[64,72) w_fc2[72,80); ffmid[32,64) (over dead qkv)
// V-transpose is fused into gemm8<_,1> (qkv GEMM) epilogue in ALL paths.
extern "C" void kernel_launch(void* const* d_in, const int* in_sizes, int n_in,
                              void* d_out, int out_size, void* d_ws, size_t ws_size,
                              hipStream_t stream) {
  const float* x        = (const float*)d_in[0];
  const float* ln1_w    = (const float*)d_in[1];
  const float* ln1_b    = (const float*)d_in[2];
  const float* in_proj_w= (const float*)d_in[3];
  const float* in_proj_b= (const float*)d_in[4];
  const float* out_w    = (const float*)d_in[5];
  const float* out_b    = (const float*)d_in[6];
  const float* ln2_w    = (const float*)d_in[7];
  const float* ln2_b    = (const float*)d_in[8];
  const float* fc1_w    = (const float*)d_in[9];
  const float* fc1_b    = (const float*)d_in[10];
  const float* fc2_w    = (const float*)d_in[11];
  const float* fc2_b    = (const float*)d_in[12];
  const int*   prefix   = (const int*)d_in[13];
  float* outp = (float*)d_out;

  char* ws = (char*)d_ws;
  unsigned short* slab  = (unsigned short*)ws;                          // [0,8)
  float*          x2    = (float*)(ws + ((size_t)8 << 20));             // [8,24)
  unsigned short* vtb   = (unsigned short*)(ws + ((size_t)8 << 20));    // [8,16) alias
  unsigned short* wslab = (unsigned short*)(ws + ((size_t)24 << 20));   // [24,32)
  unsigned short* qkv   = (unsigned short*)(ws + ((size_t)32 << 20));   // [32,56)
  unsigned short* wfc2  = (unsigned short*)(ws + ((size_t)32 << 20));   // [32,40) alias
  unsigned short* ffh   = (unsigned short*)(ws + ((size_t)40 << 20));   // [40,56) alias
  const bool big = ws_size >= ((size_t)72 << 20);
  const bool wd  = ws_size >= ((size_t)80 << 20);

  // wd layout pointers
  unsigned short* w_in  = (unsigned short*)(ws + ((size_t)24 << 20));   // [24,30)
  unsigned short* w_out = (unsigned short*)(ws + ((size_t)30 << 20));   // [30,32)
  unsigned short* w_fc1 = (unsigned short*)(ws + ((size_t)64 << 20));   // [64,72)
  unsigned short* w_fc2 = (unsigned short*)(ws + ((size_t)72 << 20));   // [72,80)
  unsigned short* ffm32 = (unsigned short*)(ws + ((size_t)32 << 20));   // [32,64)

  // --- prep: LN1 + weight conversion ---
  if (wd) {
    prep_kernel<<<MM + 1024, 256, 0, stream>>>(x, ln1_w, ln1_b, slab,
                                               in_proj_w, w_in, 3072 * 1024 / 4,
                                               out_w, w_out, 1024 * 1024 / 4,
                                               fc1_w, w_fc1, 4096 * 1024 / 4,
                                               fc2_w, w_fc2, 1024 * 4096 / 4);
  } else {
    convert_f32_bf16<<<3072, 256, 0, stream>>>(in_proj_w, wslab, 3072 * 1024 / 4);
    ln_kernel<<<MM, 256, 0, stream>>>(x, ln1_w, ln1_b, slab);
  }

  // --- attention half (V-transpose fused into qkv GEMM epilogue) ---
  gemm8<0, 1><<<dim3(3072 / 256, MM / 256), 512, 0, stream>>>(slab, wd ? w_in : wslab, in_proj_b, qkv, vtb, MM, 3072, 1024, 1024, 1024);
  attn_kernel<<<dim3(LL / 128, BB * NH), 512, 0, stream>>>(qkv, vtb, prefix, slab);
  if (!wd) convert_f32_bf16<<<1024, 256, 0, stream>>>(out_w, wslab, 1024 * 1024 / 4);
  gemm_bt<1, 64><<<dim3(1024 / 64, MM / 64), 256, 0, stream>>>(slab, wd ? w_out : wslab, out_b, x, x2, MM, 1024, 1024, 1024, 1024);

  // --- FFN ---
  ln_kernel<<<MM, 256, 0, stream>>>(x2, ln2_w, ln2_b, slab);
  if (wd) {
    gemm8<2, 0><<<dim3(4096 / 256, MM / 256), 512, 0, stream>>>(slab, w_fc1, fc1_b, ffm32, nullptr, MM, 4096, 1024, 1024, 1024);
    gemm_bt<1, 64><<<dim3(1024 / 64, MM / 64), 256, 0, stream>>>(ffm32, w_fc2, fc2_b, x2, outp, MM, 1024, 4096, 4096, 4096);
  } else {
    convert_f32_bf16<<<4096, 256, 0, stream>>>(fc1_w, wslab, 4096 * 1024 / 4);
    convert_f32_bf16<<<4096, 256, 0, stream>>>(fc2_w, wfc2, 1024 * 4096 / 4);  // qkv dead
    if (big) {
      unsigned short* ffmid = (unsigned short*)(ws + ((size_t)40 << 20));
      gemm8<2, 0><<<dim3(4096 / 256, MM / 256), 512, 0, stream>>>(slab, wslab, fc1_b, ffmid, nullptr, MM, 4096, 1024, 1024, 1024);
      gemm_bt<1, 64><<<dim3(1024 / 64, MM / 64), 256, 0, stream>>>(ffmid, wfc2, fc2_b, x2, outp, MM, 1024, 4096, 4096, 4096);
    } else {
      gemm_bt<2, 128><<<dim3(2048 / 64, MM / 128), 256, 0, stream>>>(slab, wslab, fc1_b, nullptr, ffh, MM, 2048, 1024, 1024, 1024);
      gemm_bt<1, 64><<<dim3(1024 / 64, MM / 64), 256, 0, stream>>>(ffh, wfc2, fc2_b, x2, outp, MM, 1024, 2048, 2048, 4096);
      gemm_bt<2, 128><<<dim3(2048 / 64, MM / 128), 256, 0, stream>>>(slab, wslab + (size_t)2048 * 1024, fc1_b + 2048, nullptr, ffh, MM, 2048, 1024, 1024, 1024);
      gemm_bt<3, 64><<<dim3(1024 / 64, MM / 64), 256, 0, stream>>>(ffh, wfc2 + 2048, nullptr, nullptr, outp, MM, 1024, 2048, 2048, 4096);
    }
  }
}